// Round 10
// baseline (170.433 us; speedup 1.0000x reference)
//
#include <hip/hip_runtime.h>
#include <hip/hip_bf16.h>
#include <math.h>

#define IH 48
#define IW 48
#define NN 2304          // N = IH*IW
#define CC 256           // channels
#define NH 8
#define HD 32
#define HID 1024
#define NBIAS 9025       // (2*48-1)^2
#define SCALE 0.17677669529663687f
#define LOG2E 1.4426950408889634f
#define LN_EPS 1e-5f

typedef __attribute__((ext_vector_type(8))) short bf16x8;   // 8 bf16 in 4 VGPRs
typedef __attribute__((ext_vector_type(4))) float f32x4;

__device__ __forceinline__ short f2b(float f) {
    __hip_bfloat16 h = __float2bfloat16(f);
    short s; __builtin_memcpy(&s, &h, 2); return s;
}
__device__ __forceinline__ float b2f(short s) {
    __hip_bfloat16 h; __builtin_memcpy(&h, &s, 2); return __bfloat162float(h);
}
__device__ __forceinline__ float fast_exp2(float x) {
#if __has_builtin(__builtin_amdgcn_exp2f)
    return __builtin_amdgcn_exp2f(x);     // single v_exp_f32
#else
    return exp2f(x);
#endif
}

// ------- Prep (single launch): ln1 | coalesced weight transpose | bias -----
// blocks [0,NN): LayerNorm rows.
// blocks [NN, NN+768): 32x32-tile f32->bf16 transposes (both sides coalesced).
// blocks [NN+768, ...): bias table [9025][8] -> [8][9025] bf16 * LOG2E.
__global__ void prep_kernel(const float* __restrict__ x, const float* __restrict__ g,
                            const float* __restrict__ b, short* __restrict__ t1,
                            const float* __restrict__ bt, short* __restrict__ o_bias,
                            const float* __restrict__ w_qkv, const float* __restrict__ w_proj,
                            const float* __restrict__ w_fc1, const float* __restrict__ w_fc2,
                            short* __restrict__ o_qkv, short* __restrict__ o_proj,
                            short* __restrict__ o_fc1, short* __restrict__ o_fc2)
{
    __shared__ float tsh[32][33];
    __shared__ float red[8];
    const int bid = blockIdx.x, tid = threadIdx.x;
    if (bid < NN) {        // ---- LayerNorm row ----
        float v = x[bid * CC + tid];
        float s = v, s2 = v * v;
        #pragma unroll
        for (int off = 32; off > 0; off >>= 1) {
            s  += __shfl_xor(s, off);
            s2 += __shfl_xor(s2, off);
        }
        const int wid = tid >> 6;
        if ((tid & 63) == 0) { red[wid * 2] = s; red[wid * 2 + 1] = s2; }
        __syncthreads();
        float tot  = red[0] + red[2] + red[4] + red[6];
        float tot2 = red[1] + red[3] + red[5] + red[7];
        float mu   = tot * (1.0f / CC);
        float var  = tot2 * (1.0f / CC) - mu * mu;
        float rstd = rsqrtf(var + LN_EPS);
        t1[bid * CC + tid] = f2b((v - mu) * rstd * g[tid] + b[tid]);
        return;
    }
    if (bid < NN + 768) {  // ---- weight transpose tile ----
        int bb = bid - NN;
        const float* src; short* dst; int K, Nn, kt, nt;
        if (bb < 192)      { src = w_qkv;  dst = o_qkv;  K = 256;  Nn = 768;  kt = bb / 24; nt = bb % 24; }
        else if (bb < 256) { bb -= 192; src = w_proj; dst = o_proj; K = 256;  Nn = 256;  kt = bb / 8;  nt = bb % 8; }
        else if (bb < 512) { bb -= 256; src = w_fc1;  dst = o_fc1;  K = 256;  Nn = 1024; kt = bb / 32; nt = bb % 32; }
        else               { bb -= 512; src = w_fc2;  dst = o_fc2;  K = 1024; Nn = 256;  kt = bb / 8;  nt = bb % 8; }
        const int r = tid >> 5, c = tid & 31;
        const int k0 = kt * 32, n0 = nt * 32;
        #pragma unroll
        for (int i = 0; i < 4; ++i)
            tsh[r + i * 8][c] = src[(k0 + r + i * 8) * Nn + n0 + c];
        __syncthreads();
        #pragma unroll
        for (int i = 0; i < 4; ++i)
            dst[(n0 + r + i * 8) * K + k0 + c] = f2b(tsh[c][r + i * 8]);
        return;
    }
    // ---- bias table conversion, read-coalesced ----
    const int stride = (gridDim.x - NN - 768) * 256;
    for (int i = (bid - NN - 768) * 256 + tid; i < NBIAS * NH; i += stride) {
        int idx = i >> 3, h = i & 7;
        o_bias[h * NBIAS + idx] = f2b(bt[i] * LOG2E);
    }
}

// --- MFMA GEMM core: TM x 64 tile, TM/16 waves, K-step 64, reg-pipelined ---
#define GSTRIDE 72
template<int KLEN, int KSTR, int TM>
__device__ __forceinline__ void mfma_gemm_core(const short* __restrict__ A,
                                               const short* __restrict__ BT,
                                               int m0, int n0, int kb, f32x4 acc[4],
                                               short* lds)
{
    short* As = lds;                 // [TM][72]
    short* Bs = lds + TM * GSTRIDE;  // [64][72]
    const int tid  = threadIdx.x;
    const int w    = tid >> 6, lane = tid & 63;
    const int quad = lane >> 4, l15 = lane & 15;
    const int sr = tid >> 2;            // A staging row 0..TM-1 (threads/4==TM)
    const int sc = (tid & 3) * 16;      // k-granule 0,16,32,48
    #pragma unroll
    for (int c = 0; c < 4; ++c) acc[c] = (f32x4){0.f, 0.f, 0.f, 0.f};

    const short* Ap = &A [(m0 + sr) * KSTR + kb + sc];
    const short* Bp = &BT[(n0 + sr) * KSTR + kb + sc];
    bf16x8 ra0 = *(const bf16x8*)Ap,       ra1 = *(const bf16x8*)(Ap + 8);
    bf16x8 rb0 = *(const bf16x8*)Bp,       rb1 = *(const bf16x8*)(Bp + 8);
    bf16x8 rc0, rc1;
    const short* Bp2 = Bp;
    if constexpr (TM == 32) {           // second B-row block (rows 32..63)
        Bp2 = &BT[(n0 + sr + 32) * KSTR + kb + sc];
        rc0 = *(const bf16x8*)Bp2;  rc1 = *(const bf16x8*)(Bp2 + 8);
    }

    for (int k0 = 0; k0 < KLEN; k0 += 64) {
        __syncthreads();                       // LDS consumers of tile k-1 done
        *(bf16x8*)&As[sr * GSTRIDE + sc]     = ra0;
        *(bf16x8*)&As[sr * GSTRIDE + sc + 8] = ra1;
        *(bf16x8*)&Bs[sr * GSTRIDE + sc]     = rb0;
        *(bf16x8*)&Bs[sr * GSTRIDE + sc + 8] = rb1;
        if constexpr (TM == 32) {
            *(bf16x8*)&Bs[(sr + 32) * GSTRIDE + sc]     = rc0;
            *(bf16x8*)&Bs[(sr + 32) * GSTRIDE + sc + 8] = rc1;
        }
        if (k0 + 64 < KLEN) {                  // prefetch tile k+1 (overlaps below)
            ra0 = *(const bf16x8*)(Ap + k0 + 64);
            ra1 = *(const bf16x8*)(Ap + k0 + 72);
            rb0 = *(const bf16x8*)(Bp + k0 + 64);
            rb1 = *(const bf16x8*)(Bp + k0 + 72);
            if constexpr (TM == 32) {
                rc0 = *(const bf16x8*)(Bp2 + k0 + 64);
                rc1 = *(const bf16x8*)(Bp2 + k0 + 72);
            }
        }
        __syncthreads();                       // tile k visible
        #pragma unroll
        for (int s = 0; s < 2; ++s) {
            bf16x8 a = *(const bf16x8*)&As[(w * 16 + l15) * GSTRIDE + s * 32 + quad * 8];
            #pragma unroll
            for (int c = 0; c < 4; ++c) {
                bf16x8 b = *(const bf16x8*)&Bs[(c * 16 + l15) * GSTRIDE + s * 32 + quad * 8];
                acc[c] = __builtin_amdgcn_mfma_f32_16x16x32_bf16(a, b, acc[c], 0, 0, 0);
            }
        }
    }
}
// C/D layout [m89]: col = n-tile*16 + (lane&15), row = 16w + quad*4 + reg.

// ---------------- QKV: t1 @ w_qkvT -> qb, kb (bf16 [h][n][d]), vT [h][d][n]-
// q is pre-scaled by SCALE*LOG2E so attention softmax can use exp2 directly.
__global__ void qkv_kernel(const short* __restrict__ t1, const short* __restrict__ wT,
                           short* __restrict__ qb, short* __restrict__ kb,
                           short* __restrict__ vT)
{
    __shared__ short lds[2 * 64 * GSTRIDE];
    f32x4 acc[4];
    const int m0 = blockIdx.y * 64, n0 = blockIdx.x * 64;
    mfma_gemm_core<256, 256, 64>(t1, wT, m0, n0, 0, acc, lds);
    const int lane = threadIdx.x & 63, w = threadIdx.x >> 6;
    const int quad = lane >> 4, l15 = lane & 15;
    #pragma unroll
    for (int c = 0; c < 4; ++c) {
        int col = n0 + c * 16 + l15;
        int three = col >> 8, rem = col & 255;
        int h = rem >> 5, d = rem & 31;
        #pragma unroll
        for (int r = 0; r < 4; ++r) {
            int row = m0 + w * 16 + quad * 4 + r;
            float v = acc[c][r];
            if (three == 0)      qb[(h * NN + row) * HD + d] = f2b(v * (SCALE * LOG2E));
            else if (three == 1) kb[(h * NN + row) * HD + d] = f2b(v);
            else                 vT[(h * HD + d) * NN + row] = f2b(v);
        }
    }
}

// -------- MFMA flash attention: round-8 structure (session best) -----------
// block=(head,16q), 4 waves x 576 keys, P via per-wave LDS round-trip.
// Bias: 48x63 bf16 window staged coalesced once per block (validated r4->5).
#define PSTRIDE 40    // sbuf row stride: 80 B (16B-aligned, conflict-free b128)
__global__ __launch_bounds__(256) void attn_kernel(
        const short* __restrict__ qb, const short* __restrict__ kb,
        const short* __restrict__ vT, const short* __restrict__ biasT,
        short* __restrict__ o)
{
    __shared__ float Ored[4][16][33];
    __shared__ float lred[4][16];
    __shared__ short sbuf[4][16 * PSTRIDE];
    __shared__ short bwin[48][64];
    const int w = threadIdx.x >> 6, lane = threadIdx.x & 63;
    const int quad = lane >> 4, l15 = lane & 15;
    const int h = blockIdx.x / 144, q0 = (blockIdx.x % 144) * 16;
    const int t0 = w * 576;
    short* sb = &sbuf[w][0];
    const short* bt = &biasT[h * NBIAS];

    // per-block q coords: 16-row q-tiles never straddle image rows (16 | 48)
    const int qi = q0 / IW, qj0 = q0 % IW;

    // ---- stage the 48x63 bias window, coalesced ----
    for (int idx = threadIdx.x; idx < 48 * 63; idx += 256) {
        int kr = idx / 63, cc = idx - kr * 63;
        bwin[kr][cc] = bt[(qi - kr + 47) * 95 + qj0 + cc];
    }

    // Q fragment: A[m=lane&15][k=quad*8+j]  (q pre-scaled by SCALE*LOG2E)
    bf16x8 qf = *(const bf16x8*)&qb[(h * NN + q0 + l15) * HD + quad * 8];

    f32x4 O0 = (f32x4){0.f,0.f,0.f,0.f}, O1 = (f32x4){0.f,0.f,0.f,0.f};
    float lp[4] = {0.f, 0.f, 0.f, 0.f};
    const f32x4 zero = (f32x4){0.f,0.f,0.f,0.f};

    __syncthreads();                       // bias window visible

    for (int c = 0; c < 18; ++c) {
        const int t = t0 + c * 32;
        bf16x8 k0f = *(const bf16x8*)&kb[(h * NN + t      + l15) * HD + quad * 8];
        bf16x8 k1f = *(const bf16x8*)&kb[(h * NN + t + 16 + l15) * HD + quad * 8];
        f32x4 s0 = __builtin_amdgcn_mfma_f32_16x16x32_bf16(qf, k0f, zero, 0, 0, 0);
        f32x4 s1 = __builtin_amdgcn_mfma_f32_16x16x32_bf16(qf, k1f, zero, 0, 0, 0);
        bf16x8 v0 = *(const bf16x8*)&vT[(h * HD + l15)      * NN + t + quad * 8];
        bf16x8 v1 = *(const bf16x8*)&vT[(h * HD + 16 + l15) * NN + t + quad * 8];

        // bias from LDS window: 16-key halves never straddle image rows
        const int ki0 = t / IW,        kj0_ = t - ki0 * IW;
        const int ki1 = (t + 16) / IW, kj1_ = (t + 16) - ki1 * IW;
        const int cA = quad * 4 + 47 - kj0_ - l15;
        const int cB = quad * 4 + 47 - kj1_ - l15;

        #pragma unroll
        for (int r = 0; r < 4; ++r) {
            float p0 = fast_exp2(s0[r] + b2f(bwin[ki0][cA + r]));
            float p1 = fast_exp2(s1[r] + b2f(bwin[ki1][cB + r]));
            lp[r] += p0 + p1;
            sb[(quad * 4 + r) * PSTRIDE + l15]      = f2b(p0);
            sb[(quad * 4 + r) * PSTRIDE + 16 + l15] = f2b(p1);
        }
        // Per-wave private LDS round-trip; DS pipe is in-order within a wave.
        asm volatile("s_waitcnt lgkmcnt(0)" ::: "memory");
        bf16x8 pa = *(const bf16x8*)&sb[l15 * PSTRIDE + quad * 8];
        O0 = __builtin_amdgcn_mfma_f32_16x16x32_bf16(pa, v0, O0, 0, 0, 0);
        O1 = __builtin_amdgcn_mfma_f32_16x16x32_bf16(pa, v1, O1, 0, 0, 0);
    }

    #pragma unroll
    for (int r = 0; r < 4; ++r) {
        float l = lp[r];
        l += __shfl_xor(l, 1); l += __shfl_xor(l, 2);
        l += __shfl_xor(l, 4); l += __shfl_xor(l, 8);
        if (l15 == 0) lred[w][quad * 4 + r] = l;
        Ored[w][quad * 4 + r][l15]      = O0[r];
        Ored[w][quad * 4 + r][16 + l15] = O1[r];
    }
    __syncthreads();
    {   // 256 threads combine 16 q-rows x 32 dims (2 rows per thread)
        const int col = threadIdx.x & 31;
        for (int rr = threadIdx.x >> 5; rr < 16; rr += 8) {
            float s = 0.f, l = 0.f;
            #pragma unroll
            for (int pw = 0; pw < 4; ++pw) { s += Ored[pw][rr][col]; l += lred[pw][rr]; }
            o[(q0 + rr) * CC + h * HD + col] = f2b(s / l);
        }
    }
}

// ------- proj: o @ w_projT + b_proj + x -> x2 (fp32), 32-row tiles ---------
// Grid (4,72) = 288 blocks of 128 threads (2x the old 144 at zero extra cost).
__global__ void proj_kernel(const short* __restrict__ o, const short* __restrict__ wT,
                            const float* __restrict__ bias, const float* __restrict__ x_in,
                            float* __restrict__ x2)
{
    __shared__ short lds[(32 + 64) * GSTRIDE];
    f32x4 acc[4];
    const int m0 = blockIdx.y * 32, n0 = blockIdx.x * 64;
    mfma_gemm_core<256, 256, 32>(o, wT, m0, n0, 0, acc, lds);
    const int lane = threadIdx.x & 63, w = threadIdx.x >> 6;
    const int quad = lane >> 4, l15 = lane & 15;
    #pragma unroll
    for (int c = 0; c < 4; ++c) {
        int col = n0 + c * 16 + l15;
        #pragma unroll
        for (int r = 0; r < 4; ++r) {
            int row = m0 + w * 16 + quad * 4 + r;
            x2[row * CC + col] = acc[c][r] + bias[col] + x_in[row * CC + col];
        }
    }
}

// ------- fc1 with INLINE LN2: x2 -> stats -> LN -> GEMM -> GELU -> h1 ------
// Round-9 lesson: the only moves that beat round 0 were consolidation.
// ln_kernel is folded here: a cheap stats pre-pass over this block's 64 rows
// (full 256-col LN rows == the A-tile), then (v-mu)*rstd*g+b applied during
// A-staging. Removes one launch + the t2 write/read round-trip (2.4 MB).
__global__ __launch_bounds__(256) void fc1_kernel(
        const float* __restrict__ x2, const short* __restrict__ wT,
        const float* __restrict__ g2, const float* __restrict__ b2,
        const float* __restrict__ bias, short* __restrict__ h1)
{
    __shared__ short lds[2 * 64 * GSTRIDE];
    __shared__ float muS[64], rsS[64];
    short* As = lds;
    short* Bs = lds + 64 * GSTRIDE;
    const int tid = threadIdx.x;
    const int w = tid >> 6, lane = tid & 63;
    const int quad = lane >> 4, l15 = lane & 15;
    const int m0 = blockIdx.y * 64, n0 = blockIdx.x * 64;

    // ---- LN2 stats: 4 threads per row, 64 fp32 each, shuffle-combined ----
    {
        const int row = tid >> 2, cb = (tid & 3) * 64;
        const float* xr = &x2[(m0 + row) * CC + cb];
        float s = 0.f, q = 0.f;
        #pragma unroll
        for (int j = 0; j < 16; ++j) {
            f32x4 v = *(const f32x4*)(xr + j * 4);
            s += (v[0] + v[1]) + (v[2] + v[3]);
            q += (v[0] * v[0] + v[1] * v[1]) + (v[2] * v[2] + v[3] * v[3]);
        }
        s += __shfl_xor(s, 1); s += __shfl_xor(s, 2);
        q += __shfl_xor(q, 1); q += __shfl_xor(q, 2);
        if ((tid & 3) == 0) {
            float mu  = s * (1.0f / CC);
            float var = q * (1.0f / CC) - mu * mu;
            muS[row] = mu;
            rsS[row] = rsqrtf(var + LN_EPS);
        }
    }
    __syncthreads();

    const int sr = tid >> 2, sc = (tid & 3) * 16;
    const float mu = muS[sr], rs = rsS[sr];
    f32x4 acc[4];
    #pragma unroll
    for (int c = 0; c < 4; ++c) acc[c] = (f32x4){0.f, 0.f, 0.f, 0.f};

    const float* Ap = &x2[(m0 + sr) * CC + sc];
    const short* Bp = &wT[(n0 + sr) * CC + sc];
    f32x4 av[4];
    #pragma unroll
    for (int j = 0; j < 4; ++j) av[j] = *(const f32x4*)(Ap + j * 4);
    bf16x8 rb0 = *(const bf16x8*)Bp, rb1 = *(const bf16x8*)(Bp + 8);

    for (int k0 = 0; k0 < 256; k0 += 64) {
        __syncthreads();                       // LDS consumers of tile k-1 done
        {   // LN applied during A-staging (per-lane cols k0+sc..k0+sc+15)
            const float* gp = &g2[k0 + sc];
            const float* bp = &b2[k0 + sc];
            f32x4 gv[4], bv[4];
            #pragma unroll
            for (int j = 0; j < 4; ++j) {
                gv[j] = *(const f32x4*)(gp + j * 4);
                bv[j] = *(const f32x4*)(bp + j * 4);
            }
            bf16x8 lo, hi;
            #pragma unroll
            for (int j = 0; j < 8; ++j) {
                float vA = av[j >> 2][j & 3];
                float vB = av[2 + (j >> 2)][j & 3];
                lo[j] = f2b((vA - mu) * rs * gv[j >> 2][j & 3] + bv[j >> 2][j & 3]);
                hi[j] = f2b((vB - mu) * rs * gv[2 + (j >> 2)][j & 3] + bv[2 + (j >> 2)][j & 3]);
            }
            *(bf16x8*)&As[sr * GSTRIDE + sc]     = lo;
            *(bf16x8*)&As[sr * GSTRIDE + sc + 8] = hi;
        }
        *(bf16x8*)&Bs[sr * GSTRIDE + sc]     = rb0;
        *(bf16x8*)&Bs[sr * GSTRIDE + sc + 8] = rb1;
        if (k0 + 64 < 256) {                   // prefetch tile k+1
            #pragma unroll
            for (int j = 0; j < 4; ++j) av[j] = *(const f32x4*)(Ap + k0 + 64 + j * 4);
            rb0 = *(const bf16x8*)(Bp + k0 + 64);
            rb1 = *(const bf16x8*)(Bp + k0 + 72);
        }
        __syncthreads();                       // tile k visible
        #pragma unroll
        for (int s = 0; s < 2; ++s) {
            bf16x8 a = *(const bf16x8*)&As[(w * 16 + l15) * GSTRIDE + s * 32 + quad * 8];
            #pragma unroll
            for (int c = 0; c < 4; ++c) {
                bf16x8 b = *(const bf16x8*)&Bs[(c * 16 + l15) * GSTRIDE + s * 32 + quad * 8];
                acc[c] = __builtin_amdgcn_mfma_f32_16x16x32_bf16(a, b, acc[c], 0, 0, 0);
            }
        }
    }
    #pragma unroll
    for (int c = 0; c < 4; ++c) {
        int col = n0 + c * 16 + l15;
        #pragma unroll
        for (int r = 0; r < 4; ++r) {
            int row = m0 + w * 16 + quad * 4 + r;
            float v = acc[c][r] + bias[col];
            float ge = 0.5f * v * (1.0f + erff(v * 0.7071067811865476f));
            h1[row * HID + col] = f2b(ge);
        }
    }
}

// ------- fc2: h1 @ w_fc2T + b_fc2 + x2 -> out (fp32), 32-row tiles ---------
// Grid (4,72) = 288 blocks of 128 threads.
__global__ void fc2_kernel(const short* __restrict__ h1, const short* __restrict__ wT,
                           const float* __restrict__ bias, const float* __restrict__ x2,
                           float* __restrict__ out)
{
    __shared__ short lds[(32 + 64) * GSTRIDE];
    f32x4 acc[4];
    const int m0 = blockIdx.y * 32, n0 = blockIdx.x * 64;
    mfma_gemm_core<1024, 1024, 32>(h1, wT, m0, n0, 0, acc, lds);
    const int lane = threadIdx.x & 63, w = threadIdx.x >> 6;
    const int quad = lane >> 4, l15 = lane & 15;
    #pragma unroll
    for (int c = 0; c < 4; ++c) {
        int col = n0 + c * 16 + l15;
        #pragma unroll
        for (int r = 0; r < 4; ++r) {
            int row = m0 + w * 16 + quad * 4 + r;
            out[row * CC + col] = acc[c][r] + bias[col] + x2[row * CC + col];
        }
    }
}

extern "C" void kernel_launch(void* const* d_in, const int* in_sizes, int n_in,
                              void* d_out, int out_size, void* d_ws, size_t ws_size,
                              hipStream_t stream)
{
    const float* x          = (const float*)d_in[0];
    const float* gamma1     = (const float*)d_in[1];
    const float* beta1      = (const float*)d_in[2];
    const float* w_qkv      = (const float*)d_in[3];
    const float* w_proj     = (const float*)d_in[4];
    const float* b_proj     = (const float*)d_in[5];
    const float* bias_table = (const float*)d_in[6];
    const float* gamma2     = (const float*)d_in[7];
    const float* beta2      = (const float*)d_in[8];
    const float* w_fc1      = (const float*)d_in[9];
    const float* b_fc1      = (const float*)d_in[10];
    const float* w_fc2      = (const float*)d_in[11];
    const float* b_fc2      = (const float*)d_in[12];
    // d_in[13] = rel_idx (int32) — unused: bias index computed analytically.

    short* S = (short*)d_ws;
    const int NC = NN * CC;               // 589824
    short* t1     = S;                    // bf16 [N][C]
    short* qb     = t1  + NC;             // bf16 [h][n][d]
    short* kb     = qb  + NC;             // bf16 [h][n][d]
    short* vT     = kb  + NC;             // bf16 [h][d][n]
    short* obuf   = vT  + NC;             // bf16 [N][C]
    short* h1     = obuf+ NC;             // bf16 [N][HID]
    short* wTqkv  = h1  + NN * HID;       // bf16 [768][256]
    short* wTproj = wTqkv  + 768 * 256;   // bf16 [256][256]
    short* wTfc1  = wTproj + 256 * 256;   // bf16 [1024][256]
    short* wTfc2  = wTfc1  + 1024 * 256;  // bf16 [256][1024]
    short* biasT  = wTfc2  + 256 * 1024;  // bf16 [NH][9025] (pre-scaled by LOG2E)
    float* x2     = (float*)(biasT + NH * NBIAS + 8);  // fp32 [N][C]

    prep_kernel<<<NN + 768 + 64, 256, 0, stream>>>(x, gamma1, beta1, t1,
                                                   bias_table, biasT,
                                                   w_qkv, w_proj, w_fc1, w_fc2,
                                                   wTqkv, wTproj, wTfc1, wTfc2);
    qkv_kernel<<<dim3(12, 36), 256, 0, stream>>>(t1, wTqkv, qb, kb, vT);
    attn_kernel<<<1152, 256, 0, stream>>>(qb, kb, vT, biasT, obuf);
    proj_kernel<<<dim3(4, 72), 128, 0, stream>>>(obuf, wTproj, b_proj, x, x2);
    fc1_kernel<<<dim3(16, 36), 256, 0, stream>>>(x2, wTfc1, gamma2, beta2,
                                                 b_fc1, h1);
    fc2_kernel<<<dim3(4, 72), 128, 0, stream>>>(h1, wTfc2, b_fc2, x2,
                                                (float*)d_out);
}

// Round 11
// 159.936 us; speedup vs baseline: 1.0656x; 1.0656x over previous
//
#include <hip/hip_runtime.h>
#include <hip/hip_bf16.h>
#include <math.h>

#define IH 48
#define IW 48
#define NN 2304          // N = IH*IW
#define CC 256           // channels
#define NH 8
#define HD 32
#define HID 1024
#define NBIAS 9025       // (2*48-1)^2
#define SCALE 0.17677669529663687f
#define LOG2E 1.4426950408889634f
#define LN_EPS 1e-5f

typedef __attribute__((ext_vector_type(8))) short bf16x8;   // 8 bf16 in 4 VGPRs
typedef __attribute__((ext_vector_type(4))) float f32x4;

__device__ __forceinline__ short f2b(float f) {
    __hip_bfloat16 h = __float2bfloat16(f);
    short s; __builtin_memcpy(&s, &h, 2); return s;
}
__device__ __forceinline__ float b2f(short s) {
    __hip_bfloat16 h; __builtin_memcpy(&h, &s, 2); return __bfloat162float(h);
}
__device__ __forceinline__ float fast_exp2(float x) {
#if __has_builtin(__builtin_amdgcn_exp2f)
    return __builtin_amdgcn_exp2f(x);     // single v_exp_f32
#else
    return exp2f(x);
#endif
}

// ------- Prep (single launch): ln1 | coalesced weight transpose | bias -----
// blocks [0,NN): LayerNorm rows.
// blocks [NN, NN+768): 32x32-tile f32->bf16 transposes (both sides coalesced).
// blocks [NN+768, ...): bias table [9025][8] -> [8][9025] bf16 * LOG2E.
__global__ void prep_kernel(const float* __restrict__ x, const float* __restrict__ g,
                            const float* __restrict__ b, short* __restrict__ t1,
                            const float* __restrict__ bt, short* __restrict__ o_bias,
                            const float* __restrict__ w_qkv, const float* __restrict__ w_proj,
                            const float* __restrict__ w_fc1, const float* __restrict__ w_fc2,
                            short* __restrict__ o_qkv, short* __restrict__ o_proj,
                            short* __restrict__ o_fc1, short* __restrict__ o_fc2)
{
    __shared__ float tsh[32][33];
    __shared__ float red[8];
    const int bid = blockIdx.x, tid = threadIdx.x;
    if (bid < NN) {        // ---- LayerNorm row ----
        float v = x[bid * CC + tid];
        float s = v, s2 = v * v;
        #pragma unroll
        for (int off = 32; off > 0; off >>= 1) {
            s  += __shfl_xor(s, off);
            s2 += __shfl_xor(s2, off);
        }
        const int wid = tid >> 6;
        if ((tid & 63) == 0) { red[wid * 2] = s; red[wid * 2 + 1] = s2; }
        __syncthreads();
        float tot  = red[0] + red[2] + red[4] + red[6];
        float tot2 = red[1] + red[3] + red[5] + red[7];
        float mu   = tot * (1.0f / CC);
        float var  = tot2 * (1.0f / CC) - mu * mu;
        float rstd = rsqrtf(var + LN_EPS);
        t1[bid * CC + tid] = f2b((v - mu) * rstd * g[tid] + b[tid]);
        return;
    }
    if (bid < NN + 768) {  // ---- weight transpose tile ----
        int bb = bid - NN;
        const float* src; short* dst; int K, Nn, kt, nt;
        if (bb < 192)      { src = w_qkv;  dst = o_qkv;  K = 256;  Nn = 768;  kt = bb / 24; nt = bb % 24; }
        else if (bb < 256) { bb -= 192; src = w_proj; dst = o_proj; K = 256;  Nn = 256;  kt = bb / 8;  nt = bb % 8; }
        else if (bb < 512) { bb -= 256; src = w_fc1;  dst = o_fc1;  K = 256;  Nn = 1024; kt = bb / 32; nt = bb % 32; }
        else               { bb -= 512; src = w_fc2;  dst = o_fc2;  K = 1024; Nn = 256;  kt = bb / 8;  nt = bb % 8; }
        const int r = tid >> 5, c = tid & 31;
        const int k0 = kt * 32, n0 = nt * 32;
        #pragma unroll
        for (int i = 0; i < 4; ++i)
            tsh[r + i * 8][c] = src[(k0 + r + i * 8) * Nn + n0 + c];
        __syncthreads();
        #pragma unroll
        for (int i = 0; i < 4; ++i)
            dst[(n0 + r + i * 8) * K + k0 + c] = f2b(tsh[c][r + i * 8]);
        return;
    }
    // ---- bias table conversion, read-coalesced ----
    const int stride = (gridDim.x - NN - 768) * 256;
    for (int i = (bid - NN - 768) * 256 + tid; i < NBIAS * NH; i += stride) {
        int idx = i >> 3, h = i & 7;
        o_bias[h * NBIAS + idx] = f2b(bt[i] * LOG2E);
    }
}

// ---------------- LayerNorm (standalone, for ln2) --------------------------
__global__ void ln_kernel(const float* __restrict__ x,
                          const float* __restrict__ g,
                          const float* __restrict__ b,
                          short* __restrict__ out)
{
    __shared__ float red[8];
    const int row = blockIdx.x, tid = threadIdx.x;
    float v = x[row * CC + tid];
    float s = v, s2 = v * v;
    #pragma unroll
    for (int off = 32; off > 0; off >>= 1) {
        s  += __shfl_xor(s, off);
        s2 += __shfl_xor(s2, off);
    }
    const int wid = tid >> 6;
    if ((tid & 63) == 0) { red[wid * 2] = s; red[wid * 2 + 1] = s2; }
    __syncthreads();
    float tot  = red[0] + red[2] + red[4] + red[6];
    float tot2 = red[1] + red[3] + red[5] + red[7];
    float mu   = tot * (1.0f / CC);
    float var  = tot2 * (1.0f / CC) - mu * mu;
    float rstd = rsqrtf(var + LN_EPS);
    out[row * CC + tid] = f2b((v - mu) * rstd * g[tid] + b[tid]);
}

// --- MFMA GEMM core: TM x 64 tile, TM/16 waves, K-step 64, reg-pipelined ---
// TM=64: 256 threads (4 waves). TM=32: 128 threads (2 waves) -> 2x blocks,
// finer distribution for grid-starved GEMMs (mechanism validated r7->8).
#define GSTRIDE 72
template<int KLEN, int KSTR, int TM>
__device__ __forceinline__ void mfma_gemm_core(const short* __restrict__ A,
                                               const short* __restrict__ BT,
                                               int m0, int n0, int kb, f32x4 acc[4],
                                               short* lds)
{
    short* As = lds;                 // [TM][72]
    short* Bs = lds + TM * GSTRIDE;  // [64][72]
    const int tid  = threadIdx.x;
    const int w    = tid >> 6, lane = tid & 63;
    const int quad = lane >> 4, l15 = lane & 15;
    const int sr = tid >> 2;            // A staging row 0..TM-1 (threads/4==TM)
    const int sc = (tid & 3) * 16;      // k-granule 0,16,32,48
    #pragma unroll
    for (int c = 0; c < 4; ++c) acc[c] = (f32x4){0.f, 0.f, 0.f, 0.f};

    const short* Ap = &A [(m0 + sr) * KSTR + kb + sc];
    const short* Bp = &BT[(n0 + sr) * KSTR + kb + sc];
    bf16x8 ra0 = *(const bf16x8*)Ap,       ra1 = *(const bf16x8*)(Ap + 8);
    bf16x8 rb0 = *(const bf16x8*)Bp,       rb1 = *(const bf16x8*)(Bp + 8);
    bf16x8 rc0, rc1;
    const short* Bp2 = Bp;
    if constexpr (TM == 32) {           // second B-row block (rows 32..63)
        Bp2 = &BT[(n0 + sr + 32) * KSTR + kb + sc];
        rc0 = *(const bf16x8*)Bp2;  rc1 = *(const bf16x8*)(Bp2 + 8);
    }

    for (int k0 = 0; k0 < KLEN; k0 += 64) {
        __syncthreads();                       // LDS consumers of tile k-1 done
        *(bf16x8*)&As[sr * GSTRIDE + sc]     = ra0;
        *(bf16x8*)&As[sr * GSTRIDE + sc + 8] = ra1;
        *(bf16x8*)&Bs[sr * GSTRIDE + sc]     = rb0;
        *(bf16x8*)&Bs[sr * GSTRIDE + sc + 8] = rb1;
        if constexpr (TM == 32) {
            *(bf16x8*)&Bs[(sr + 32) * GSTRIDE + sc]     = rc0;
            *(bf16x8*)&Bs[(sr + 32) * GSTRIDE + sc + 8] = rc1;
        }
        if (k0 + 64 < KLEN) {                  // prefetch tile k+1 (overlaps below)
            ra0 = *(const bf16x8*)(Ap + k0 + 64);
            ra1 = *(const bf16x8*)(Ap + k0 + 72);
            rb0 = *(const bf16x8*)(Bp + k0 + 64);
            rb1 = *(const bf16x8*)(Bp + k0 + 72);
            if constexpr (TM == 32) {
                rc0 = *(const bf16x8*)(Bp2 + k0 + 64);
                rc1 = *(const bf16x8*)(Bp2 + k0 + 72);
            }
        }
        __syncthreads();                       // tile k visible
        #pragma unroll
        for (int s = 0; s < 2; ++s) {
            bf16x8 a = *(const bf16x8*)&As[(w * 16 + l15) * GSTRIDE + s * 32 + quad * 8];
            #pragma unroll
            for (int c = 0; c < 4; ++c) {
                bf16x8 b = *(const bf16x8*)&Bs[(c * 16 + l15) * GSTRIDE + s * 32 + quad * 8];
                acc[c] = __builtin_amdgcn_mfma_f32_16x16x32_bf16(a, b, acc[c], 0, 0, 0);
            }
        }
    }
}
// C/D layout [m89]: col = n-tile*16 + (lane&15), row = 16w + quad*4 + reg.

// ---------------- QKV: t1 @ w_qkvT -> qb, kb (bf16 [h][n][d]), vT [h][d][n]-
// q is pre-scaled by SCALE*LOG2E so attention softmax can use exp2 directly.
// TM=32: grid (12,72) x 128 threads — 864 blocks (was 432 x 256 thr).
__global__ void qkv_kernel(const short* __restrict__ t1, const short* __restrict__ wT,
                           short* __restrict__ qb, short* __restrict__ kb,
                           short* __restrict__ vT)
{
    __shared__ short lds[(32 + 64) * GSTRIDE];
    f32x4 acc[4];
    const int m0 = blockIdx.y * 32, n0 = blockIdx.x * 64;
    mfma_gemm_core<256, 256, 32>(t1, wT, m0, n0, 0, acc, lds);
    const int lane = threadIdx.x & 63, w = threadIdx.x >> 6;
    const int quad = lane >> 4, l15 = lane & 15;
    #pragma unroll
    for (int c = 0; c < 4; ++c) {
        int col = n0 + c * 16 + l15;
        int three = col >> 8, rem = col & 255;
        int h = rem >> 5, d = rem & 31;
        #pragma unroll
        for (int r = 0; r < 4; ++r) {
            int row = m0 + w * 16 + quad * 4 + r;
            float v = acc[c][r];
            if (three == 0)      qb[(h * NN + row) * HD + d] = f2b(v * (SCALE * LOG2E));
            else if (three == 1) kb[(h * NN + row) * HD + d] = f2b(v);
            else                 vT[(h * HD + d) * NN + row] = f2b(v);
        }
    }
}

// -------- MFMA flash attention: round-8 structure + setprio (T5) -----------
// block=(head,16q), 4 waves x 576 keys, P via per-wave LDS round-trip.
// Bias: 48x63 bf16 window staged coalesced once per block (validated r4->5).
// s_setprio(1) wraps the MFMA clusters only — independent blocks at different
// phases let the CU scheduler favor MFMA-entering waves (learn_hip m191).
#define PSTRIDE 40    // sbuf row stride: 80 B (16B-aligned, conflict-free b128)
__global__ __launch_bounds__(256) void attn_kernel(
        const short* __restrict__ qb, const short* __restrict__ kb,
        const short* __restrict__ vT, const short* __restrict__ biasT,
        short* __restrict__ o)
{
    __shared__ float Ored[4][16][33];
    __shared__ float lred[4][16];
    __shared__ short sbuf[4][16 * PSTRIDE];
    __shared__ short bwin[48][64];
    const int w = threadIdx.x >> 6, lane = threadIdx.x & 63;
    const int quad = lane >> 4, l15 = lane & 15;
    const int h = blockIdx.x / 144, q0 = (blockIdx.x % 144) * 16;
    const int t0 = w * 576;
    short* sb = &sbuf[w][0];
    const short* bt = &biasT[h * NBIAS];

    // per-block q coords: 16-row q-tiles never straddle image rows (16 | 48)
    const int qi = q0 / IW, qj0 = q0 % IW;

    // ---- stage the 48x63 bias window, coalesced ----
    for (int idx = threadIdx.x; idx < 48 * 63; idx += 256) {
        int kr = idx / 63, cc = idx - kr * 63;
        bwin[kr][cc] = bt[(qi - kr + 47) * 95 + qj0 + cc];
    }

    // Q fragment: A[m=lane&15][k=quad*8+j]  (q pre-scaled by SCALE*LOG2E)
    bf16x8 qf = *(const bf16x8*)&qb[(h * NN + q0 + l15) * HD + quad * 8];

    f32x4 O0 = (f32x4){0.f,0.f,0.f,0.f}, O1 = (f32x4){0.f,0.f,0.f,0.f};
    float lp[4] = {0.f, 0.f, 0.f, 0.f};
    const f32x4 zero = (f32x4){0.f,0.f,0.f,0.f};

    __syncthreads();                       // bias window visible

    for (int c = 0; c < 18; ++c) {
        const int t = t0 + c * 32;
        bf16x8 k0f = *(const bf16x8*)&kb[(h * NN + t      + l15) * HD + quad * 8];
        bf16x8 k1f = *(const bf16x8*)&kb[(h * NN + t + 16 + l15) * HD + quad * 8];
        __builtin_amdgcn_s_setprio(1);
        f32x4 s0 = __builtin_amdgcn_mfma_f32_16x16x32_bf16(qf, k0f, zero, 0, 0, 0);
        f32x4 s1 = __builtin_amdgcn_mfma_f32_16x16x32_bf16(qf, k1f, zero, 0, 0, 0);
        __builtin_amdgcn_s_setprio(0);
        bf16x8 v0 = *(const bf16x8*)&vT[(h * HD + l15)      * NN + t + quad * 8];
        bf16x8 v1 = *(const bf16x8*)&vT[(h * HD + 16 + l15) * NN + t + quad * 8];

        // bias from LDS window: 16-key halves never straddle image rows
        const int ki0 = t / IW,        kj0_ = t - ki0 * IW;
        const int ki1 = (t + 16) / IW, kj1_ = (t + 16) - ki1 * IW;
        const int cA = quad * 4 + 47 - kj0_ - l15;
        const int cB = quad * 4 + 47 - kj1_ - l15;

        #pragma unroll
        for (int r = 0; r < 4; ++r) {
            float p0 = fast_exp2(s0[r] + b2f(bwin[ki0][cA + r]));
            float p1 = fast_exp2(s1[r] + b2f(bwin[ki1][cB + r]));
            lp[r] += p0 + p1;
            sb[(quad * 4 + r) * PSTRIDE + l15]      = f2b(p0);
            sb[(quad * 4 + r) * PSTRIDE + 16 + l15] = f2b(p1);
        }
        // Per-wave private LDS round-trip; DS pipe is in-order within a wave.
        asm volatile("s_waitcnt lgkmcnt(0)" ::: "memory");
        bf16x8 pa = *(const bf16x8*)&sb[l15 * PSTRIDE + quad * 8];
        __builtin_amdgcn_s_setprio(1);
        O0 = __builtin_amdgcn_mfma_f32_16x16x32_bf16(pa, v0, O0, 0, 0, 0);
        O1 = __builtin_amdgcn_mfma_f32_16x16x32_bf16(pa, v1, O1, 0, 0, 0);
        __builtin_amdgcn_s_setprio(0);
    }

    #pragma unroll
    for (int r = 0; r < 4; ++r) {
        float l = lp[r];
        l += __shfl_xor(l, 1); l += __shfl_xor(l, 2);
        l += __shfl_xor(l, 4); l += __shfl_xor(l, 8);
        if (l15 == 0) lred[w][quad * 4 + r] = l;
        Ored[w][quad * 4 + r][l15]      = O0[r];
        Ored[w][quad * 4 + r][16 + l15] = O1[r];
    }
    __syncthreads();
    {   // 256 threads combine 16 q-rows x 32 dims (2 rows per thread)
        const int col = threadIdx.x & 31;
        for (int rr = threadIdx.x >> 5; rr < 16; rr += 8) {
            float s = 0.f, l = 0.f;
            #pragma unroll
            for (int pw = 0; pw < 4; ++pw) { s += Ored[pw][rr][col]; l += lred[pw][rr]; }
            o[(q0 + rr) * CC + h * HD + col] = f2b(s / l);
        }
    }
}

// ------- proj: o @ w_projT + b_proj + x -> x2 (fp32), 32-row tiles ---------
// Grid (4,72) = 288 blocks of 128 threads.
__global__ void proj_kernel(const short* __restrict__ o, const short* __restrict__ wT,
                            const float* __restrict__ bias, const float* __restrict__ x_in,
                            float* __restrict__ x2)
{
    __shared__ short lds[(32 + 64) * GSTRIDE];
    f32x4 acc[4];
    const int m0 = blockIdx.y * 32, n0 = blockIdx.x * 64;
    mfma_gemm_core<256, 256, 32>(o, wT, m0, n0, 0, acc, lds);
    const int lane = threadIdx.x & 63, w = threadIdx.x >> 6;
    const int quad = lane >> 4, l15 = lane & 15;
    #pragma unroll
    for (int c = 0; c < 4; ++c) {
        int col = n0 + c * 16 + l15;
        #pragma unroll
        for (int r = 0; r < 4; ++r) {
            int row = m0 + w * 16 + quad * 4 + r;
            x2[row * CC + col] = acc[c][r] + bias[col] + x_in[row * CC + col];
        }
    }
}

// ---------------- fc1: t2 @ w_fc1T + b_fc1, GELU -> h1 (bf16) --------------
// TM=32: grid (16,72) x 128 threads — 1152 blocks (was 576 x 256 thr).
__global__ void fc1_kernel(const short* __restrict__ t2, const short* __restrict__ wT,
                           const float* __restrict__ bias, short* __restrict__ h1)
{
    __shared__ short lds[(32 + 64) * GSTRIDE];
    f32x4 acc[4];
    const int m0 = blockIdx.y * 32, n0 = blockIdx.x * 64;
    mfma_gemm_core<256, 256, 32>(t2, wT, m0, n0, 0, acc, lds);
    const int lane = threadIdx.x & 63, w = threadIdx.x >> 6;
    const int quad = lane >> 4, l15 = lane & 15;
    #pragma unroll
    for (int c = 0; c < 4; ++c) {
        int col = n0 + c * 16 + l15;
        #pragma unroll
        for (int r = 0; r < 4; ++r) {
            int row = m0 + w * 16 + quad * 4 + r;
            float v = acc[c][r] + bias[col];
            float ge = 0.5f * v * (1.0f + erff(v * 0.7071067811865476f));
            h1[row * HID + col] = f2b(ge);
        }
    }
}

// ------- fc2: h1 @ w_fc2T + b_fc2 + x2 -> out (fp32), 32-row tiles ---------
// Grid (4,72) = 288 blocks of 128 threads.
__global__ void fc2_kernel(const short* __restrict__ h1, const short* __restrict__ wT,
                           const float* __restrict__ bias, const float* __restrict__ x2,
                           float* __restrict__ out)
{
    __shared__ short lds[(32 + 64) * GSTRIDE];
    f32x4 acc[4];
    const int m0 = blockIdx.y * 32, n0 = blockIdx.x * 64;
    mfma_gemm_core<1024, 1024, 32>(h1, wT, m0, n0, 0, acc, lds);
    const int lane = threadIdx.x & 63, w = threadIdx.x >> 6;
    const int quad = lane >> 4, l15 = lane & 15;
    #pragma unroll
    for (int c = 0; c < 4; ++c) {
        int col = n0 + c * 16 + l15;
        #pragma unroll
        for (int r = 0; r < 4; ++r) {
            int row = m0 + w * 16 + quad * 4 + r;
            out[row * CC + col] = acc[c][r] + bias[col] + x2[row * CC + col];
        }
    }
}

extern "C" void kernel_launch(void* const* d_in, const int* in_sizes, int n_in,
                              void* d_out, int out_size, void* d_ws, size_t ws_size,
                              hipStream_t stream)
{
    const float* x          = (const float*)d_in[0];
    const float* gamma1     = (const float*)d_in[1];
    const float* beta1      = (const float*)d_in[2];
    const float* w_qkv      = (const float*)d_in[3];
    const float* w_proj     = (const float*)d_in[4];
    const float* b_proj     = (const float*)d_in[5];
    const float* bias_table = (const float*)d_in[6];
    const float* gamma2     = (const float*)d_in[7];
    const float* beta2      = (const float*)d_in[8];
    const float* w_fc1      = (const float*)d_in[9];
    const float* b_fc1      = (const float*)d_in[10];
    const float* w_fc2      = (const float*)d_in[11];
    const float* b_fc2      = (const float*)d_in[12];
    // d_in[13] = rel_idx (int32) — unused: bias index computed analytically.

    short* S = (short*)d_ws;
    const int NC = NN * CC;               // 589824
    short* t1     = S;                    // bf16 [N][C]
    short* qb     = t1  + NC;             // bf16 [h][n][d]
    short* kb     = qb  + NC;             // bf16 [h][n][d]
    short* vT     = kb  + NC;             // bf16 [h][d][n]
    short* obuf   = vT  + NC;             // bf16 [N][C]
    short* t2     = obuf+ NC;             // bf16 [N][C]
    short* h1     = t2  + NC;             // bf16 [N][HID]
    short* wTqkv  = h1  + NN * HID;       // bf16 [768][256]
    short* wTproj = wTqkv  + 768 * 256;   // bf16 [256][256]
    short* wTfc1  = wTproj + 256 * 256;   // bf16 [1024][256]
    short* wTfc2  = wTfc1  + 1024 * 256;  // bf16 [256][1024]
    short* biasT  = wTfc2  + 256 * 1024;  // bf16 [NH][9025] (pre-scaled by LOG2E)
    float* x2     = (float*)(biasT + NH * NBIAS + 8);  // fp32 [N][C]

    prep_kernel<<<NN + 768 + 64, 256, 0, stream>>>(x, gamma1, beta1, t1,
                                                   bias_table, biasT,
                                                   w_qkv, w_proj, w_fc1, w_fc2,
                                                   wTqkv, wTproj, wTfc1, wTfc2);
    qkv_kernel<<<dim3(12, 72), 128, 0, stream>>>(t1, wTqkv, qb, kb, vT);
    attn_kernel<<<1152, 256, 0, stream>>>(qb, kb, vT, biasT, obuf);
    proj_kernel<<<dim3(4, 72), 128, 0, stream>>>(obuf, wTproj, b_proj, x, x2);
    ln_kernel<<<NN, 256, 0, stream>>>(x2, gamma2, beta2, t2);
    fc1_kernel<<<dim3(16, 72), 128, 0, stream>>>(t2, wTfc1, b_fc1, h1);
    fc2_kernel<<<dim3(4, 72), 128, 0, stream>>>(h1, wTfc2, b_fc2, x2,
                                                (float*)d_out);
}